// Round 3
// baseline (119.875 us; speedup 1.0000x reference)
//
#include <hip/hip_runtime.h>

#define BB 2
#define CC 3
#define TT 8
#define HW 448
#define AA 32
#define GG 14      // 448/32
#define RR 11      // 11x11 region grid
#define NR 121
#define NKEY 4
#define NS 500

typedef unsigned short u16;
typedef unsigned int u32;

__device__ __forceinline__ float bf2f(u16 u) {
  union { u32 i; float f; } v; v.i = ((u32)u) << 16; return v.f;
}
__device__ __forceinline__ u16 f2bf(float f) {
  union { float f; u32 i; } v; v.f = f;
  u32 u = v.i;
  return (u16)((u + 0x7fffu + ((u >> 16) & 1u)) >> 16);  // round-nearest-even
}

// Fully fused: out[b,c,t,i,j] = sum_{oi,oj in [0,11)} w[b,t,oi*11+oj] * x[b,c,t, i+32*oi, j+32*oj]
// where w = histogram/NS of argmax_r( minmaxnorm(pool4x4(score[b,gid]))[r] + sigma*noise[b*4+gid, s, r] )
// One block per (b,c,t,a1), 128 threads. No workspace, no inter-kernel dependency.
// Dtype of float tensors (f32 vs bf16) sniffed at runtime from score's bit patterns.
__global__ __launch_bounds__(128) void RegionNet_CLIP_66855460929920_kernel(
    const void* __restrict__ xv, const void* __restrict__ scorev,
    const void* __restrict__ noisev, const void* __restrict__ sigmav,
    const int* __restrict__ group_id, void* __restrict__ outv) {
  int blk = blockIdx.x;
  const int a1 = blk & (AA - 1); blk >>= 5;
  const int t = blk % TT; blk /= TT;
  const int c = blk % CC; const int b = blk / CC;
  const int tid = threadIdx.x;

  __shared__ __align__(16) float xs[GG][HW];  // 25088 B
  __shared__ float scn[NR];
  __shared__ int hist[NR];
  __shared__ float lohi[2];

  // ---- dtype sniff: score ~ uniform(0,1). bf16 bit patterns of such values
  // all lie in {0} U [0x2000, 0x3F80]; f32 mantissa halves are random.
  const u16* sh16 = (const u16*)scorev;
  bool bf_ok = true;
#pragma unroll
  for (int i = 0; i < 16; i++) {
    const u16 v = sh16[i];
    if (!(v == 0 || (v >= 0x2000 && v <= 0x3F80))) bf_ok = false;
  }
  const bool is_f32 = !bf_ok;

  const int k = group_id[b * TT + t];
  const int bk = b * NKEY + k;

  // ---- stage the 14 needed x rows {a1+32g} into LDS as f32
  if (is_f32) {
    const float* xb = (const float*)xv + ((size_t)((b * CC + c) * TT + t)) * (HW * HW);
    for (int i = tid; i < GG * (HW / 4); i += 128) {
      const int g = i / (HW / 4);
      const int c4 = i - g * (HW / 4);
      const float4 v = *(const float4*)(xb + (size_t)(a1 + AA * g) * HW + c4 * 4);
      *(float4*)(&xs[g][c4 * 4]) = v;
    }
  } else {
    const u16* xb = (const u16*)xv + ((size_t)((b * CC + c) * TT + t)) * (HW * HW);
    for (int i = tid; i < GG * (HW / 8); i += 128) {
      const int g = i / (HW / 8);
      const int c8 = i - g * (HW / 8);
      const uint4 v = *(const uint4*)(xb + (size_t)(a1 + AA * g) * HW + c8 * 8);
      float* d = &xs[g][c8 * 8];
      d[0] = bf2f((u16)(v.x & 0xffffu)); d[1] = bf2f((u16)(v.x >> 16));
      d[2] = bf2f((u16)(v.y & 0xffffu)); d[3] = bf2f((u16)(v.y >> 16));
      d[4] = bf2f((u16)(v.z & 0xffffu)); d[5] = bf2f((u16)(v.z >> 16));
      d[6] = bf2f((u16)(v.w & 0xffffu)); d[7] = bf2f((u16)(v.w >> 16));
    }
  }

  // ---- pooled 4x4-mean score -> scn[121]
  if (tid < NR) {
    hist[tid] = 0;
    const int oi = tid / RR, oj = tid - oi * RR;
    float ssum = 0.f;
    if (is_f32) {
      const float* sp = (const float*)scorev + bk * (GG * GG);
#pragma unroll
      for (int ki = 0; ki < 4; ki++)
#pragma unroll
        for (int kj = 0; kj < 4; kj++) ssum += sp[(oi + ki) * GG + (oj + kj)];
    } else {
      const u16* sp = sh16 + bk * (GG * GG);
#pragma unroll
      for (int ki = 0; ki < 4; ki++)
#pragma unroll
        for (int kj = 0; kj < 4; kj++) ssum += bf2f(sp[(oi + ki) * GG + (oj + kj)]);
    }
    scn[tid] = ssum * 0.0625f;
  }
  __syncthreads();

  // ---- min-max over the 121 entries (wave 0)
  if (tid < 64) {
    float v1 = scn[tid];
    float v2 = (tid + 64 < NR) ? scn[tid + 64] : v1;
    float mn = fminf(v1, v2), mx = fmaxf(v1, v2);
#pragma unroll
    for (int off = 32; off > 0; off >>= 1) {
      mn = fminf(mn, __shfl_xor(mn, off, 64));
      mx = fmaxf(mx, __shfl_xor(mx, off, 64));
    }
    if (tid == 0) { lohi[0] = mn; lohi[1] = mx; }
  }
  __syncthreads();
  {
    const float lo = lohi[0];
    const float denom = lohi[1] - lo + 1e-5f;
    if (tid < NR) scn[tid] = (scn[tid] - lo) / denom;
  }
  __syncthreads();

  // ---- sigma (guard against a scalar left as f32 even if arrays are bf16)
  const u32 w0 = *(const u32*)sigmav;
  float sg;
  if (is_f32) {
    union { u32 i; float f; } v; v.i = w0; sg = v.f;
  } else {
    sg = bf2f((u16)(w0 & 0xffffu));
    union { u32 i; float f; } v; v.i = w0;
    if (!(sg > -100.f && sg < 100.f) && (v.f > -100.f && v.f < 100.f)) sg = v.f;
  }

  // ---- 500-sample perturbed argmax histogram (samples across threads,
  //      regions serial per thread; strict > keeps lowest index = lax.top_k)
  if (is_f32) {
    const float* nb = (const float*)noisev + (size_t)bk * (NS * NR);
    for (int s = tid; s < NS; s += 128) {
      const float* npr = nb + (size_t)s * NR;
      float bv = scn[0] + sg * npr[0]; int bi = 0;
      for (int r = 1; r < NR; r++) {
        const float v = scn[r] + sg * npr[r];
        if (v > bv) { bv = v; bi = r; }
      }
      atomicAdd(&hist[bi], 1);
    }
  } else {
    const u16* nb = (const u16*)noisev + (size_t)bk * (NS * NR);
    for (int s = tid; s < NS; s += 128) {
      const u16* npr = nb + (size_t)s * NR;
      float bv = scn[0] + sg * bf2f(npr[0]); int bi = 0;
      for (int r = 1; r < NR; r++) {
        const float v = scn[r] + sg * bf2f(npr[r]);
        if (v > bv) { bv = v; bi = r; }
      }
      atomicAdd(&hist[bi], 1);
    }
  }
  __syncthreads();

  // ---- histogram -> weights (reuse scn)
  if (tid < NR) scn[tid] = (float)hist[tid] * (1.0f / NS);
  __syncthreads();

  // ---- weighted strided gather: thread = (ki=i/32, j/4)
  const int ki = tid >> 5;
  const int j = (tid & 31) * 4;
  float acc0 = 0.f, acc1 = 0.f, acc2 = 0.f, acc3 = 0.f;
  for (int oi = 0; oi < RR; oi++) {
    const float* xrow = &xs[ki + oi][j];
    const float* wrow = &scn[oi * RR];
#pragma unroll
    for (int oj = 0; oj < RR; oj++) {
      const float wv = wrow[oj];
      const float4 v = *(const float4*)(xrow + AA * oj);
      acc0 += wv * v.x;
      acc1 += wv * v.y;
      acc2 += wv * v.z;
      acc3 += wv * v.w;
    }
  }

  const size_t obase =
      ((size_t)((b * CC + c) * TT + t) * 128 + (ki * AA + a1)) * 128 + j;
  if (is_f32) {
    float4 st; st.x = acc0; st.y = acc1; st.z = acc2; st.w = acc3;
    *(float4*)((float*)outv + obase) = st;
  } else {
    uint2 ov;
    ov.x = (u32)f2bf(acc0) | ((u32)f2bf(acc1) << 16);
    ov.y = (u32)f2bf(acc2) | ((u32)f2bf(acc3) << 16);
    *(uint2*)((u16*)outv + obase) = ov;
  }
}

extern "C" void kernel_launch(void* const* d_in, const int* in_sizes, int n_in,
                              void* d_out, int out_size, void* d_ws, size_t ws_size,
                              hipStream_t stream) {
  const void* x = d_in[0];         // (2,3,8,448,448)
  const void* score = d_in[1];     // (2,4,196)
  const void* noise = d_in[2];     // (8,500,121)
  const void* sigma = d_in[3];     // scalar
  const int* group_id = (const int*)d_in[4];  // (2,8) int32
  (void)d_ws; (void)ws_size; (void)in_sizes; (void)n_in; (void)out_size;

  RegionNet_CLIP_66855460929920_kernel<<<dim3(BB * CC * TT * AA), 128, 0, stream>>>(
      x, score, noise, sigma, group_id, d_out);
}